// Round 13
// baseline (387.931 us; speedup 1.0000x reference)
//
#include <hip/hip_runtime.h>

#define B_   128
#define DIM_ 768
#define NH_  12
#define HD_  64
#define N_   256

using half8 = __attribute__((ext_vector_type(8))) _Float16;
using half4 = __attribute__((ext_vector_type(4))) _Float16;
using f32x4 = __attribute__((ext_vector_type(4))) float;
typedef unsigned short u16;
typedef unsigned int   u32;

#define GLDS16(srcp, dstp) \
    __builtin_amdgcn_global_load_lds( \
        (const __attribute__((address_space(1))) void*)(srcp), \
        (__attribute__((address_space(3))) void*)(dstp), 16, 0, 0)

// m204 bijective XCD swizzle
__device__ __forceinline__ int xcd_chunked(int orig, int nwg) {
    int xcd = orig & 7, loc = orig >> 3;
    int qq = nwg >> 3, rr = nwg & 7;
    return (xcd < rr ? xcd * (qq + 1) : rr * (qq + 1) + (xcd - rr) * qq) + loc;
}

// ---------------------------------------------------------------------------
// bias16 = fp16(face_prior + rel_table gather) -> [NH, N, N]
// ---------------------------------------------------------------------------
__global__ __launch_bounds__(256) void bias16_kernel(
    const float* __restrict__ face_prior, const float* __restrict__ rel_table,
    _Float16* __restrict__ b16)
{
    int gid = blockIdx.x * 256 + threadIdx.x;
    int idx = gid * 2;
    union { _Float16 s[2]; u32 u; } P;
    #pragma unroll
    for (int j = 0; j < 2; ++j) {
        int id = idx + j;
        int m = id & 255;
        int n = (id >> 8) & 255;
        int h = id >> 16;
        int rn = n >> 4, cn = n & 15;
        int rm = m >> 4, cm = m & 15;
        int ridx = (rn - rm + 15) * 31 + (cn - cm + 15);
        P.s[j] = (_Float16)(face_prior[id] + rel_table[ridx * NH_ + h]);
    }
    *(u32*)(b16 + idx) = P.u;
}

// ---------------------------------------------------------------------------
// fp32 -> fp16 linear (face_priors)
// ---------------------------------------------------------------------------
__global__ __launch_bounds__(256) void conv_f32_f16(
    const float* __restrict__ in, _Float16* __restrict__ o16, int n8)
{
    int i = blockIdx.x * 256 + threadIdx.x;
    if (i >= n8) return;
    float4 a = *(const float4*)(in + (size_t)i * 8);
    float4 b = *(const float4*)(in + (size_t)i * 8 + 4);
    float v[8] = {a.x, a.y, a.z, a.w, b.x, b.y, b.z, b.w};
    union { _Float16 s[8]; uint4 q; } H;
    #pragma unroll
    for (int j = 0; j < 8; ++j) H.s[j] = (_Float16)v[j];
    *(uint4*)(o16 + (size_t)i * 8) = H.q;
}

// ---------------------------------------------------------------------------
// proj_w fp32 [6*128][768] -> fp16 OLD staged [6][24][512][8] (128-row tiles)
// ---------------------------------------------------------------------------
__global__ __launch_bounds__(256) void conv_w_f16_staged(
    const float* __restrict__ in, _Float16* __restrict__ o16, int nchunk)
{
    int gid = blockIdx.x * 256 + threadIdx.x;
    if (gid >= nchunk) return;
    int t   = gid / 12288;          // 24*512
    int rem = gid % 12288;
    int ks  = rem >> 9;
    int c   = rem & 511;
    int mtb = c >> 6, kgrp = (c >> 4) & 3, r16 = c & 15;
    int srow = t * 128 + mtb * 16 + r16;
    int sk   = ks * 32 + kgrp * 8;
    float4 a = *(const float4*)(in + (size_t)srow * DIM_ + sk);
    float4 b = *(const float4*)(in + (size_t)srow * DIM_ + sk + 4);
    float v[8] = {a.x, a.y, a.z, a.w, b.x, b.y, b.z, b.w};
    union { _Float16 s[8]; uint4 q; } H;
    #pragma unroll
    for (int j = 0; j < 8; ++j) H.s[j] = (_Float16)v[j];
    *(uint4*)(o16 + (size_t)gid * 8) = H.q;
}

// ---------------------------------------------------------------------------
// qkv_w fp32 [9*256][768] -> fp16 NEW staged [9][24][1024][8] (256-row tiles)
// chunk c = mtb*64 + kg*16 + r16 ; row = mtb*16+r16, k = ks*32 + kg*8 + koff
// ---------------------------------------------------------------------------
__global__ __launch_bounds__(256) void conv_qw_staged(
    const float* __restrict__ in, _Float16* __restrict__ o16, int nchunk)
{
    int gid = blockIdx.x * 256 + threadIdx.x;
    if (gid >= nchunk) return;
    int t   = gid / 24576;          // 24*1024
    int rem = gid % 24576;
    int ks  = rem >> 10;
    int c   = rem & 1023;
    int mtb = c >> 6, kg = (c >> 4) & 3, r16 = c & 15;
    int srow = t * 256 + mtb * 16 + r16;
    int sk   = ks * 32 + kg * 8;
    float4 a = *(const float4*)(in + (size_t)srow * DIM_ + sk);
    float4 b = *(const float4*)(in + (size_t)srow * DIM_ + sk + 4);
    float v[8] = {a.x, a.y, a.z, a.w, b.x, b.y, b.z, b.w};
    union { _Float16 s[8]; uint4 q; } H;
    #pragma unroll
    for (int j = 0; j < 8; ++j) H.s[j] = (_Float16)v[j];
    *(uint4*)(o16 + (size_t)gid * 8) = H.q;
}

// ---------------------------------------------------------------------------
// x [B,768(k),256(n)] fp32 -> fp16 NEW staged [B][24][1024][8]
// ---------------------------------------------------------------------------
__global__ __launch_bounds__(256) void conv_transpose_x_f16(
    const float* __restrict__ x, _Float16* __restrict__ xa)
{
    __shared__ float T[64][65];
    const int b = blockIdx.z, k0 = blockIdx.x * 64, n0 = blockIdx.y * 64;
    const int t = threadIdx.x;
    const float* xb = x + (size_t)b * DIM_ * N_;
    {
        int nn = t & 63, kg = t >> 6;
        #pragma unroll
        for (int r = 0; r < 16; ++r) {
            int kk = r * 4 + kg;
            T[kk][nn] = xb[(size_t)(k0 + kk) * N_ + n0 + nn];
        }
    }
    __syncthreads();
    {
        int kk2 = (t & 31) * 2, ng = t >> 5;
        #pragma unroll
        for (int r = 0; r < 8; ++r) {
            int nn = r * 8 + ng;
            union { _Float16 s[2]; u32 u; } P;
            P.s[0] = (_Float16)T[kk2][nn];
            P.s[1] = (_Float16)T[kk2 + 1][nn];
            int n = n0 + nn, k = k0 + kk2;
            int ks = k >> 5, kg = (k >> 3) & 3, koff = k & 7;
            int mtb = n >> 4, r16 = n & 15;
            size_t o = (((size_t)b * 24 + ks) * 1024
                        + mtb * 64 + kg * 16 + r16) * 8 + koff;
            *(u32*)(xa + o) = P.u;
        }
    }
}

// ---------------------------------------------------------------------------
// QKV GEMM v2: 256x256 tile, 8 waves (512 thr), BK=32, 3-slot LDS pipeline
// with COUNTED vmcnt (T3/T4): tiles staged 3 ahead via global_load_lds; per
// iteration vmcnt(8) waits only tile t's 4 loads (t+1/t+2 stay in flight
// across the barriers); raw s_barrier (no compiler vmcnt(0) drain).
// Slot freed by barrier2, then restaged. LDS 96KB (3x16KB A + 3x16KB B).
// grid cb*9 (XCD-chunked, by fastest).
// ---------------------------------------------------------------------------
__global__ __launch_bounds__(512) void qkv_gemm(
    const _Float16* __restrict__ w16, const _Float16* __restrict__ x16,
    const float* __restrict__ bvec,
    _Float16* __restrict__ q16, _Float16* __restrict__ k16,
    _Float16* __restrict__ v16,
    int b0, int cb)
{
    extern __shared__ _Float16 lds[];          // [3][8192] A | [3][8192] B

    const int tid  = threadIdx.x;
    const int lane = tid & 63;
    const int wv   = tid >> 6;                 // 0..7
    const int wr   = wv >> 2;                  // oc half (0..1)
    const int wc   = wv & 3;                   // n quarter (0..3)

    const int wg = xcd_chunked(blockIdx.x, cb * 9);
    const int by = wg % 9;                     // oc tile (fast -> share X in L2)
    const int bl = wg / 9;
    const int b  = b0 + bl;

    const _Float16* wbase = w16 + (size_t)by * 24 * 8192;
    const _Float16* xbase = x16 + (size_t)b  * 24 * 8192;

    f32x4 acc[8][4];
    #pragma unroll
    for (int i = 0; i < 8; ++i)
        #pragma unroll
        for (int j = 0; j < 4; ++j)
            acc[i][j] = (f32x4){0.f, 0.f, 0.f, 0.f};

    const int sbase = wv * 512;                // wave-uniform elem offset

#define STAGE_T(tt, slot) do { \
        const _Float16* ws_ = wbase + (size_t)(tt) * 8192; \
        const _Float16* xs_ = xbase + (size_t)(tt) * 8192; \
        _Float16* da_ = lds + (slot) * 8192; \
        _Float16* db_ = lds + 24576 + (slot) * 8192; \
        GLDS16(ws_ + sbase + lane * 8,        da_ + sbase); \
        GLDS16(ws_ + 4096 + sbase + lane * 8, da_ + 4096 + sbase); \
        GLDS16(xs_ + sbase + lane * 8,        db_ + sbase); \
        GLDS16(xs_ + 4096 + sbase + lane * 8, db_ + 4096 + sbase); \
    } while (0)

    STAGE_T(0, 0); STAGE_T(1, 1); STAGE_T(2, 2);   // 12 loads in flight

    int slot = 0;
    for (int t = 0; t < 24; ++t) {
        // counted wait: retire tile t's 4 loads; keep younger tiles in flight
        if (t < 22)       asm volatile("s_waitcnt vmcnt(8)" ::: "memory");
        else if (t == 22) asm volatile("s_waitcnt vmcnt(4)" ::: "memory");
        else              asm volatile("s_waitcnt vmcnt(0)" ::: "memory");
        __builtin_amdgcn_s_barrier();

        const _Float16* SAs = lds + slot * 8192;
        const _Float16* SBs = lds + 24576 + slot * 8192;
        half8 af[8];
        #pragma unroll
        for (int mt = 0; mt < 8; ++mt)
            af[mt] = *(const half8*)&SAs[((wr * 8 + mt) * 64 + lane) * 8];
        #pragma unroll
        for (int nt = 0; nt < 4; ++nt) {
            half8 bf = *(const half8*)&SBs[((wc * 4 + nt) * 64 + lane) * 8];
            #pragma unroll
            for (int mt = 0; mt < 8; ++mt)
                acc[mt][nt] = __builtin_amdgcn_mfma_f32_16x16x32_f16(af[mt], bf, acc[mt][nt], 0, 0, 0);
        }
        __builtin_amdgcn_s_barrier();          // all waves done with slot

        if (t + 3 < 24) STAGE_T(t + 3, slot);  // refill freed slot, no wait
        slot = (slot == 2) ? 0 : slot + 1;
    }
#undef STAGE_T

    // C/D layout: col = lane&15 (n), row = (lane>>4)*4 + reg (oc)
    const int which = by / 3;                  // 0:q 1:k 2:v (uniform)
    _Float16* slab = (which == 0) ? q16 : (which == 1) ? k16 : v16;
    const int ocr0 = (by % 3) * 256 + wr * 128 + ((lane >> 4) << 2);
    const int nb   = wc * 64 + (lane & 15);

    #pragma unroll
    for (int mt = 0; mt < 8; ++mt) {
        int oc_in = ocr0 + mt * 16;            // within [0,768)
        float4 bv = *(const float4*)(bvec + which * DIM_ + oc_in);
        int hh = oc_in >> 6, d = oc_in & 63;
        size_t rowbase = ((size_t)bl * NH_ + hh) * (size_t)(N_ * HD_) + d;
        #pragma unroll
        for (int nt = 0; nt < 4; ++nt) {
            int n = nb + nt * 16;
            union { _Float16 s[4]; uint2 u; } H;
            H.s[0] = (_Float16)(acc[mt][nt][0] + bv.x);
            H.s[1] = (_Float16)(acc[mt][nt][1] + bv.y);
            H.s[2] = (_Float16)(acc[mt][nt][2] + bv.z);
            H.s[3] = (_Float16)(acc[mt][nt][3] + bv.w);
            *(uint2*)(slab + rowbase + (size_t)n * HD_) = H.u;
        }
    }
}

// ---------------------------------------------------------------------------
// MFMA attention v3 (unchanged from r12)
// ---------------------------------------------------------------------------
__global__ __launch_bounds__(256) void attn_mfma(
    const _Float16* __restrict__ q16, const _Float16* __restrict__ k16,
    const _Float16* __restrict__ v16,
    const _Float16* __restrict__ bias16, const _Float16* __restrict__ fpri16,
    _Float16* __restrict__ ao,
    int b0, int cb)
{
    extern __shared__ _Float16 ldsh[];
    _Float16* KL  = ldsh;                     // [256][64], idx = r*64 + (kc ^ ((r&7)<<3))
    _Float16* VtL = ldsh + 16384;             // [64][256], idx = d*256 + (kk ^ ((d&7)<<3))
    const int tid  = threadIdx.x;
    const int lane = tid & 63;
    const int wv   = tid >> 6;                // 0..3
    _Float16* PL = ldsh + 32768 + wv * 512;   // [16][32] per wave

    const int bh = xcd_chunked(blockIdx.x, cb * NH_);
    const int bl = bh / NH_, h = bh % NH_;
    const int b  = b0 + bl;
    const size_t base = ((size_t)bl * NH_ + h) * (size_t)(N_ * HD_);

    const int l15 = lane & 15;
    const int lg  = lane >> 4;
    const int e   = (l15 & 3) << 1;           // PL swizzle

    #pragma unroll
    for (int s = 0; s < 8; ++s) {
        int idx = tid + s * 256;              // 0..2047
        int r = idx >> 3, kc = (idx & 7) * 8;
        *(half8*)&KL[r * 64 + (kc ^ ((r & 7) << 3))] =
            *(const half8*)(k16 + base + (size_t)r * 64 + kc);
    }
    #pragma unroll
    for (int s = 0; s < 8; ++s) {
        int idx = tid + s * 256;
        int d = idx & 63, kkc = (idx >> 6) * 8;
        union { _Float16 sv[8]; half8 v; } t;
        #pragma unroll
        for (int j = 0; j < 8; ++j)
            t.sv[j] = v16[base + (size_t)(kkc + j) * 64 + d];
        *(half8*)&VtL[d * 256 + (kkc ^ ((d & 7) << 3))] = t.v;
    }
    __syncthreads();

    for (int qt = 0; qt < 4; ++qt) {
        const int qg = wv * 64 + qt * 16 + l15;
        const size_t qrow = base + (size_t)qg * 64;
        half8 bq[2];
        #pragma unroll
        for (int c = 0; c < 2; ++c)
            bq[c] = *(const half8*)(q16 + qrow + lg * 8 + c * 32);

        const _Float16* brow = bias16 + ((size_t)h * N_ + qg) * N_;
        const _Float16* frow = fpri16 + ((size_t)b * N_ + qg) * N_;

        float mrun = -1e30f, lrun = 0.f;
        f32x4 oacc[4];
        #pragma unroll
        for (int dt = 0; dt < 4; ++dt) oacc[dt] = (f32x4){0.f, 0.f, 0.f, 0.f};

        for (int ch = 0; ch < 2; ++ch) {
            f32x4 sacc[8];
            #pragma unroll
            for (int kt = 0; kt < 8; ++kt) {
                f32x4 sa = (f32x4){0.f, 0.f, 0.f, 0.f};
                int kr = ch * 128 + kt * 16 + l15;
                #pragma unroll
                for (int c = 0; c < 2; ++c) {
                    int kc = lg * 8 + c * 32;
                    half8 ah = *(const half8*)&KL[kr * 64 + (kc ^ ((kr & 7) << 3))];
                    sa = __builtin_amdgcn_mfma_f32_16x16x32_f16(ah, bq[c], sa, 0, 0, 0);
                }
                half4 bsv = *(const half4*)(brow + ch * 128 + kt * 16 + lg * 4);
                half4 fsv = *(const half4*)(frow + ch * 128 + kt * 16 + lg * 4);
                sacc[kt][0] = (sa[0] * 0.125f + (float)bsv[0]) * (float)fsv[0];
                sacc[kt][1] = (sa[1] * 0.125f + (float)bsv[1]) * (float)fsv[1];
                sacc[kt][2] = (sa[2] * 0.125f + (float)bsv[2]) * (float)fsv[2];
                sacc[kt][3] = (sa[3] * 0.125f + (float)bsv[3]) * (float)fsv[3];
            }

            float cmax = -1e30f;
            #pragma unroll
            for (int kt = 0; kt < 8; ++kt)
                cmax = fmaxf(cmax, fmaxf(fmaxf(sacc[kt][0], sacc[kt][1]),
                                         fmaxf(sacc[kt][2], sacc[kt][3])));
            cmax = fmaxf(cmax, __shfl_xor(cmax, 16));
            cmax = fmaxf(cmax, __shfl_xor(cmax, 32));
            float mnew = fmaxf(mrun, cmax);
            float corr = __expf(mrun - mnew);
            mrun = mnew;
            float csum = 0.f;
            #pragma unroll
            for (int kt = 0; kt < 8; ++kt) {
                #pragma unroll
                for (int j = 0; j < 4; ++j) {
                    float p = __expf(sacc[kt][j] - mnew);
                    sacc[kt][j] = p;
                    csum += p;
                }
            }
            csum += __shfl_xor(csum, 16);
            csum += __shfl_xor(csum, 32);
            lrun = lrun * corr + csum;
            #pragma unroll
            for (int dt = 0; dt < 4; ++dt) {
                oacc[dt][0] *= corr; oacc[dt][1] *= corr;
                oacc[dt][2] *= corr; oacc[dt][3] *= corr;
            }

            #pragma unroll
            for (int c2 = 0; c2 < 4; ++c2) {
                #pragma unroll
                for (int t = 0; t < 2; ++t) {
                    int kt = c2 * 2 + t;
                    union { _Float16 s[4]; uint2 u; } pw;
                    pw.s[0] = (_Float16)sacc[kt][0];
                    pw.s[1] = (_Float16)sacc[kt][1];
                    pw.s[2] = (_Float16)sacc[kt][2];
                    pw.s[3] = (_Float16)sacc[kt][3];
                    int u = (4 * t + lg) ^ e;
                    *(uint2*)&PL[l15 * 32 + u * 4] = pw.u;
                }
                half8 bp = *(const half8*)&PL[l15 * 32 + ((2 * lg) ^ e) * 4];
                int kc2 = ch * 128 + c2 * 32 + lg * 8;
                #pragma unroll
                for (int dt = 0; dt < 4; ++dt) {
                    int dr = dt * 16 + l15;
                    half8 av = *(const half8*)&VtL[dr * 256 + (kc2 ^ ((dr & 7) << 3))];
                    oacc[dt] = __builtin_amdgcn_mfma_f32_16x16x32_f16(av, bp, oacc[dt], 0, 0, 0);
                }
            }
        }

        float inv = 1.f / lrun;
        const int hf  = qg >> 7, mtb = (qg >> 4) & 7, r16 = qg & 15;
        #pragma unroll
        for (int dt = 0; dt < 4; ++dt) {
            int k = h * 64 + dt * 16 + lg * 4;
            int ks = k >> 5, kgrp = (k >> 3) & 3, koff = k & 7;
            size_t off = ((((size_t)(bl * 2 + hf) * 24 + ks) * 512)
                          + mtb * 64 + kgrp * 16 + r16) * 8 + koff;
            union { _Float16 s[4]; uint2 u; } H;
            #pragma unroll
            for (int j = 0; j < 4; ++j)
                H.s[j] = (_Float16)(oacc[dt][j] * inv);
            *(uint2*)(ao + off) = H.u;
        }
    }
}

// ---------------------------------------------------------------------------
// Proj GEMM (unchanged from r12): fp16, old staged layout, gload_lds,
// XCD-chunked 1D grid. grid cb*12.
// ---------------------------------------------------------------------------
__global__ __launch_bounds__(256) void proj_gemm(
    const _Float16* __restrict__ wst, const _Float16* __restrict__ ao,
    const float* __restrict__ bvec, float* __restrict__ outp,
    int b0, int cb)
{
    __shared__ __align__(16) _Float16 SW[4096], SX[4096];

    const int tid  = threadIdx.x;
    const int lane = tid & 63;
    const int wv   = tid >> 6;
    const int wr   = wv >> 1;
    const int wc   = wv & 1;

    const int wg = xcd_chunked(blockIdx.x, cb * 12);
    const int by = wg % 6;
    const int bx = wg / 6;
    const int bl = bx >> 1, half = bx & 1;
    const int b  = b0 + bl;

    const size_t wq0 = (size_t)by * 24 * 4096;
    const size_t xq0 = ((size_t)bl * 2 + half) * 24 * 4096;

    f32x4 acc[4][4];
    #pragma unroll
    for (int i = 0; i < 4; ++i)
        #pragma unroll
        for (int j = 0; j < 4; ++j)
            acc[i][j] = (f32x4){0.f, 0.f, 0.f, 0.f};

    const int d0 = wv * 512;

    for (int ks = 0; ks < 24; ++ks) {
        const size_t wq = wq0 + (size_t)ks * 4096 + d0;
        const size_t xq = xq0 + (size_t)ks * 4096 + d0;
        #pragma unroll
        for (int s = 0; s < 2; ++s) {
            GLDS16(wst + wq + s * 2048 + lane * 8, &SW[d0 + s * 2048]);
            GLDS16(ao  + xq + s * 2048 + lane * 8, &SX[d0 + s * 2048]);
        }
        __syncthreads();

        half8 ah[4];
        #pragma unroll
        for (int mt = 0; mt < 4; ++mt)
            ah[mt] = *(const half8*)&SW[((wr * 4 + mt) * 64 + lane) * 8];
        #pragma unroll
        for (int nt = 0; nt < 4; ++nt) {
            half8 bh = *(const half8*)&SX[((wc * 4 + nt) * 64 + lane) * 8];
            #pragma unroll
            for (int mt = 0; mt < 4; ++mt)
                acc[mt][nt] = __builtin_amdgcn_mfma_f32_16x16x32_f16(ah[mt], bh, acc[mt][nt], 0, 0, 0);
        }
        __syncthreads();
    }

    const int ocb = by * 128 + wr * 64 + (lane >> 4) * 4;
    const int nb  = half * 128 + wc * 64 + (lane & 15);

    #pragma unroll
    for (int mt = 0; mt < 4; ++mt) {
        int oc = ocb + mt * 16;
        float4 bv = *(const float4*)(bvec + oc);
        float* obase = outp + (size_t)b * DIM_ * N_ + (size_t)oc * N_;
        #pragma unroll
        for (int nt = 0; nt < 4; ++nt) {
            int n = nb + nt * 16;
            obase[0 * N_ + n] = acc[mt][nt][0] + bv.x;
            obase[1 * N_ + n] = acc[mt][nt][1] + bv.y;
            obase[2 * N_ + n] = acc[mt][nt][2] + bv.z;
            obase[3 * N_ + n] = acc[mt][nt][3] + bv.w;
        }
    }
}

// ---------------------------------------------------------------------------
extern "C" void kernel_launch(void* const* d_in, const int* in_sizes, int n_in,
                              void* d_out, int out_size, void* d_ws, size_t ws_size,
                              hipStream_t stream)
{
    const float* x           = (const float*)d_in[0];
    const float* face_priors = (const float*)d_in[1];
    const float* qkv_w       = (const float*)d_in[2];
    const float* qkv_b       = (const float*)d_in[3];
    const float* rel_table   = (const float*)d_in[4];
    const float* face_prior  = (const float*)d_in[5];
    const float* proj_w      = (const float*)d_in[6];
    const float* proj_b      = (const float*)d_in[7];
    float* out = (float*)d_out;

    _Float16* b16   = (_Float16*)d_ws;
    _Float16* fp16p = b16 + (size_t)NH_ * N_ * N_;
    _Float16* xa16  = fp16p + (size_t)B_ * N_ * N_;
    _Float16* qw16  = xa16 + (size_t)B_ * N_ * DIM_;
    _Float16* pw16  = qw16 + (size_t)3 * DIM_ * DIM_;
    _Float16* cbase = pw16 + (size_t)DIM_ * DIM_;

    const size_t PERSIST = 2ull * (NH_ * N_ * N_ + (size_t)B_ * N_ * N_
                         + (size_t)B_ * N_ * DIM_ + 4ull * DIM_ * DIM_);
    int CB = 1;
    const int cands[] = {128, 64, 32, 16, 8, 4, 2, 1};
    for (int ci = 0; ci < 8; ++ci) {
        if (PERSIST + (size_t)cands[ci] * 1572864ull <= ws_size) { CB = cands[ci]; break; }
    }
    const size_t SL = (size_t)CB * NH_ * N_ * HD_;
    _Float16* q16b = cbase;
    _Float16* k16b = q16b + SL;
    _Float16* v16b = k16b + SL;
    _Float16* aob  = v16b + SL;

    hipFuncSetAttribute((const void*)attn_mfma,
                        hipFuncAttributeMaxDynamicSharedMemorySize, 69632);
    hipFuncSetAttribute((const void*)qkv_gemm,
                        hipFuncAttributeMaxDynamicSharedMemorySize, 98304);

    bias16_kernel<<<(NH_ * N_ * N_ / 2) / 256, 256, 0, stream>>>(face_prior, rel_table, b16);
    conv_f32_f16<<<((B_ * N_ * N_ / 8) + 255) / 256, 256, 0, stream>>>(face_priors, fp16p, B_ * N_ * N_ / 8);
    conv_qw_staged<<<(9 * 24576 + 255) / 256, 256, 0, stream>>>(qkv_w, qw16, 9 * 24576);
    conv_w_f16_staged<<<(6 * 12288 + 255) / 256, 256, 0, stream>>>(proj_w, pw16, 6 * 12288);
    conv_transpose_x_f16<<<dim3(12, 4, B_), 256, 0, stream>>>(x, xa16);

    for (int b0 = 0; b0 < B_; b0 += CB) {
        qkv_gemm<<<CB * 9, 512, 98304, stream>>>(
            qw16, xa16, qkv_b, q16b, k16b, v16b, b0, CB);

        attn_mfma<<<CB * NH_, 256, 69632, stream>>>(
            q16b, k16b, v16b, b16, fp16p, aob, b0, CB);

        proj_gemm<<<CB * 12, 256, 0, stream>>>(
            pw16, aob, proj_b, out, b0, CB);
    }
}